// Round 3
// baseline (118.504 us; speedup 1.0000x reference)
//
#include <hip/hip_runtime.h>
#include <math.h>

#define B 4
#define HW 76800       // 240*320
#define NBINS 256
#define NC 257         // bins + pad center
#define K1_BLOCKS 300
#define K2_BPB 150     // blocks per batch (150*256*2 == 76800 exactly)
#define P 2            // pixels per thread
#define TPB 256
#define PXB (TPB * P)  // 512 pixels per block
#define NBLK2 (K2_BPB * B)   // 600

// ws layout (4-byte words):
//   [0, 600)       : K1 per-block {maxT, maxC} pairs (plain stores, kmax -> kmain)
//   [600, 1628)    : dir1 per-(b,m) running min (uint bits, atomicMin), init +inf by kmax
//   [1628, 1632)   : dir2 per-batch sums (float, atomicAdd), init 0 by kmax
//   [1632]         : done-counter (uint), init 0 by kmax
#define WS_MAX_OFF  0
#define WS_DIR1_OFF 600
#define WS_DIR2_OFF (600 + B * NC)        // 1628
#define WS_CNT_OFF  (WS_DIR2_OFF + B)     // 1632
#define N_INIT      (B * NC + B + 1)      // 1033 words to init

__global__ __launch_bounds__(256) void kmax(const float* __restrict__ target,
                                            const int* __restrict__ mask,
                                            const float* __restrict__ centers,
                                            float* __restrict__ ws) {
    const int tid = threadIdx.x;
    const int g = blockIdx.x * 256 + tid;

    // ---- init the reduction workspace (replaces the two hipMemsetAsync) ----
    if (g < N_INIT) {
        unsigned int* wsu = (unsigned int*)(ws + WS_DIR1_OFF);
        if (g < B * NC)            wsu[g] = 0x7F800000u;          // +inf bits
        else if (g < B * NC + B)   ws[WS_DIR2_OFF + (g - B * NC)] = 0.f;
        else                       wsu[B * NC + B] = 0u;          // counter
    }

    // ---- per-block masked-target max + center max ----
    const int stride = K1_BLOCKS * 256;   // 76800
    float mT = -INFINITY;
#pragma unroll
    for (int r = 0; r < 4; ++r) {         // 4*76800 = 307200 = B*HW exactly
        int i = g + r * stride;
        float v = target[i];
        if (mask[i]) mT = fmaxf(mT, v);
    }
    float mC = -INFINITY;
    if (g < B * NBINS) mC = centers[g];
    for (int o = 32; o > 0; o >>= 1) {
        mT = fmaxf(mT, __shfl_down(mT, o));
        mC = fmaxf(mC, __shfl_down(mC, o));
    }
    __shared__ float sT[4], sC[4];
    int w = tid >> 6;
    if ((tid & 63) == 0) { sT[w] = mT; sC[w] = mC; }
    __syncthreads();
    if (tid == 0) {
        mT = fmaxf(fmaxf(sT[0], sT[1]), fmaxf(sT[2], sT[3]));
        mC = fmaxf(fmaxf(sC[0], sC[1]), fmaxf(sC[2], sC[3]));
        ws[WS_MAX_OFF + 2 * blockIdx.x]     = mT;
        ws[WS_MAX_OFF + 2 * blockIdx.x + 1] = mC;
    }
}

__global__ __launch_bounds__(256) void kmain(const float* __restrict__ target,
                                             const int* __restrict__ mask,
                                             const float* __restrict__ centers,
                                             float* __restrict__ ws,
                                             float* __restrict__ out) {
    __shared__ __align__(16) float s_c[NC + 3];   // +3 so float4 tail read is in-bounds
    __shared__ __align__(16) float s_t[PXB];
    __shared__ float s_red[8];
    __shared__ float s_pad;
    __shared__ unsigned int s_last;
    const int tid = threadIdx.x;
    const int b   = blockIdx.y;
    const int blk = blockIdx.x;
    const int w   = tid >> 6;

    const float*  ws_max  = ws + WS_MAX_OFF;
    unsigned int* ws_dir1 = (unsigned int*)(ws + WS_DIR1_OFF);
    float*        ws_dir2 = ws + WS_DIR2_OFF;
    unsigned int* ws_cnt  = (unsigned int*)(ws + WS_CNT_OFF);

    // ---- phase 1: reduce the 300 max-pairs -> pad_value; stage centers ----
    float mT = -INFINITY, mC = -INFINITY;
    for (int i = tid; i < K1_BLOCKS; i += TPB) {
        mT = fmaxf(mT, ws_max[2 * i]);
        mC = fmaxf(mC, ws_max[2 * i + 1]);
    }
    for (int o = 32; o > 0; o >>= 1) {
        mT = fmaxf(mT, __shfl_down(mT, o));
        mC = fmaxf(mC, __shfl_down(mC, o));
    }
    if ((tid & 63) == 0) { s_red[w] = mT; s_red[4 + w] = mC; }
    if (tid < NBINS) s_c[tid] = centers[b * NBINS + tid];
    __syncthreads();
    if (tid == 0) {
        float aT = fmaxf(fmaxf(s_red[0], s_red[1]), fmaxf(s_red[2], s_red[3]));
        float aC = fmaxf(fmaxf(s_red[4], s_red[5]), fmaxf(s_red[6], s_red[7]));
        float mx = fmaxf(aT, aC), mn = fminf(aT, aC);
        float pad = mx + (mx - mn) + 1.0f;   // EPS = 1.0
        s_pad = pad;
        s_c[NBINS] = pad;                    // padded 257th center
        s_c[NBINS + 1] = pad;                // dead lanes for float4 tail
        s_c[NBINS + 2] = pad;
        s_c[NBINS + 3] = pad;
    }
    __syncthreads();
    const float pad = s_pad;

    // ---- phase 2: pixels -> registers + LDS stage ----
    const int base = b * HW + blk * PXB;
    float t[P], min2[P];
#pragma unroll
    for (int p = 0; p < P; ++p) {
        int i = base + p * TPB + tid;
        float v = target[i];
        t[p] = mask[i] ? v : pad;
        s_t[p * TPB + tid] = t[p];
        min2[p] = INFINITY;
    }
    __syncthreads();

    // ---- Loop A (dir2): per-pixel min over all 257 centers, no cross-lane ----
    const float4* s_c4 = (const float4*)s_c;
#pragma unroll 4
    for (int mq = 0; mq < 64; ++mq) {        // 64*4 = 256 real centers
        float4 c = s_c4[mq];
#pragma unroll
        for (int p = 0; p < P; ++p) {
            float d0 = t[p] - c.x, d1 = t[p] - c.y;
            float d2 = t[p] - c.z, d3 = t[p] - c.w;
            min2[p] = fminf(min2[p], fminf(fminf(d0 * d0, d1 * d1),
                                           fminf(d2 * d2, d3 * d3)));
        }
    }
    {   // pad center (index 256)
        float c = s_c[NBINS];
#pragma unroll
        for (int p = 0; p < P; ++p) {
            float d = t[p] - c;
            min2[p] = fminf(min2[p], d * d);
        }
    }

    // ---- Loop B (dir1): thread owns center tid (+256 for tid==0) ----
    const float4* s_t4 = (const float4*)s_t;
    for (int mi = tid; mi < NC; mi += TPB) {
        float c = s_c[mi];
        float cmin = INFINITY;
#pragma unroll 8
        for (int j = 0; j < PXB / 4; ++j) {
            float4 v = s_t4[j];
            float d0 = v.x - c, d1 = v.y - c, d2 = v.z - c, d3 = v.w - c;
            cmin = fminf(cmin, fminf(fminf(d0 * d0, d1 * d1),
                                     fminf(d2 * d2, d3 * d3)));
        }
        atomicMin(&ws_dir1[b * NC + mi], __float_as_uint(cmin));
    }

    // ---- dir2 per-block sum -> atomicAdd ----
    float acc = min2[0] + min2[1];
    for (int o = 32; o > 0; o >>= 1) acc += __shfl_down(acc, o);
    __syncthreads();                          // s_red reuse safe-guard
    if ((tid & 63) == 0) s_red[w] = acc;
    __syncthreads();
    if (tid == 0)
        atomicAdd(&ws_dir2[b], s_red[0] + s_red[1] + s_red[2] + s_red[3]);

    // ---- last-block final reduction (replaces kfinal) ----
    __threadfence();                          // order this thread's atomics before counter bump
    __syncthreads();
    if (tid == 0) s_last = atomicAdd(ws_cnt, 1u);
    __syncthreads();
    if (s_last == NBLK2 - 1) {
        float facc = 0.f;
        // atomic-identity reads -> device-coherent point (no cross-XCD staleness)
        for (int i = tid; i < B * NC; i += TPB)
            facc += __uint_as_float(atomicMin(&ws_dir1[i], 0xFFFFFFFFu));
        if (tid < B) facc += atomicAdd(&ws_dir2[tid], 0.0f);
        for (int o = 32; o > 0; o >>= 1) facc += __shfl_down(facc, o);
        __syncthreads();
        if ((tid & 63) == 0) s_red[w] = facc;
        __syncthreads();
        if (tid == 0)
            out[0] = (s_red[0] + s_red[1] + s_red[2] + s_red[3]) * (1.0f / B);
    }
}

extern "C" void kernel_launch(void* const* d_in, const int* in_sizes, int n_in,
                              void* d_out, int out_size, void* d_ws, size_t ws_size,
                              hipStream_t stream) {
    const float* target  = (const float*)d_in[0];
    const float* centers = (const float*)d_in[1];
    const int*   mask    = (const int*)d_in[2];
    float* out = (float*)d_out;
    float* ws  = (float*)d_ws;

    kmax<<<K1_BLOCKS, TPB, 0, stream>>>(target, mask, centers, ws);
    dim3 g2(K2_BPB, B);
    kmain<<<g2, TPB, 0, stream>>>(target, mask, centers, ws, out);
}

// Round 4
// 86.824 us; speedup vs baseline: 1.3649x; 1.3649x over previous
//
#include <hip/hip_runtime.h>
#include <math.h>

#define B 4
#define HW 76800       // 240*320
#define NBINS 256
#define NC 257         // bins + pad center
#define K1_BLOCKS 300
#define K2_BPB 150     // blocks per batch (150*256*2 == 76800 exactly)
#define P 2            // pixels per thread
#define TPB 256
#define PXB (TPB * P)  // 512 pixels per block

// ws layout (4-byte words):
//   [0, 600)       : K1 per-block {maxT, maxC} pairs (plain stores, kmax -> kmain)
//   [600, 1628)    : dir1 per-(b,m) running min (uint bits, atomicMin), init +inf by kmax
//   [1628, 1632)   : dir2 per-batch sums (float, atomicAdd), init 0 by kmax
#define WS_MAX_OFF  0
#define WS_DIR1_OFF 600
#define WS_DIR2_OFF (600 + B * NC)        // 1628
#define N_INIT      (B * NC + B)          // 1032 words to init

__global__ __launch_bounds__(256) void kmax(const float* __restrict__ target,
                                            const int* __restrict__ mask,
                                            const float* __restrict__ centers,
                                            float* __restrict__ ws) {
    const int tid = threadIdx.x;
    const int g = blockIdx.x * 256 + tid;

    // ---- init the reduction workspace (replaces hipMemsetAsync) ----
    if (g < N_INIT) {
        unsigned int* wsu = (unsigned int*)(ws + WS_DIR1_OFF);
        if (g < B * NC) wsu[g] = 0x7F800000u;                    // +inf bits
        else            ws[WS_DIR2_OFF + (g - B * NC)] = 0.f;    // dir2 zeros
    }

    // ---- per-block masked-target max + center max ----
    const int stride = K1_BLOCKS * 256;   // 76800
    float mT = -INFINITY;
#pragma unroll
    for (int r = 0; r < 4; ++r) {         // 4*76800 = 307200 = B*HW exactly
        int i = g + r * stride;
        float v = target[i];
        if (mask[i]) mT = fmaxf(mT, v);
    }
    float mC = -INFINITY;
    if (g < B * NBINS) mC = centers[g];
    for (int o = 32; o > 0; o >>= 1) {
        mT = fmaxf(mT, __shfl_down(mT, o));
        mC = fmaxf(mC, __shfl_down(mC, o));
    }
    __shared__ float sT[4], sC[4];
    int w = tid >> 6;
    if ((tid & 63) == 0) { sT[w] = mT; sC[w] = mC; }
    __syncthreads();
    if (tid == 0) {
        mT = fmaxf(fmaxf(sT[0], sT[1]), fmaxf(sT[2], sT[3]));
        mC = fmaxf(fmaxf(sC[0], sC[1]), fmaxf(sC[2], sC[3]));
        ws[WS_MAX_OFF + 2 * blockIdx.x]     = mT;
        ws[WS_MAX_OFF + 2 * blockIdx.x + 1] = mC;
    }
}

__global__ __launch_bounds__(256) void kmain(const float* __restrict__ target,
                                             const int* __restrict__ mask,
                                             const float* __restrict__ centers,
                                             float* __restrict__ ws) {
    __shared__ __align__(16) float s_c[NC + 3];   // +3 so float4 tail read is in-bounds
    __shared__ __align__(16) float s_t[PXB];
    __shared__ float s_red[8];
    __shared__ float s_pad;
    const int tid = threadIdx.x;
    const int b   = blockIdx.y;
    const int blk = blockIdx.x;
    const int w   = tid >> 6;

    const float*  ws_max  = ws + WS_MAX_OFF;
    unsigned int* ws_dir1 = (unsigned int*)(ws + WS_DIR1_OFF);
    float*        ws_dir2 = ws + WS_DIR2_OFF;

    // ---- issue pixel loads FIRST; consumed after the pad reduction so the
    //      global latency hides behind the shuffle chain ----
    const int base = b * HW + blk * PXB;
    const int i0 = base + tid, i1 = base + TPB + tid;
    float v0 = target[i0], v1 = target[i1];
    int   m0 = mask[i0],   m1 = mask[i1];

    // ---- phase 1: reduce the 300 max-pairs -> pad_value; stage centers ----
    float mT = -INFINITY, mC = -INFINITY;
    for (int i = tid; i < K1_BLOCKS; i += TPB) {
        mT = fmaxf(mT, ws_max[2 * i]);
        mC = fmaxf(mC, ws_max[2 * i + 1]);
    }
    for (int o = 32; o > 0; o >>= 1) {
        mT = fmaxf(mT, __shfl_down(mT, o));
        mC = fmaxf(mC, __shfl_down(mC, o));
    }
    if ((tid & 63) == 0) { s_red[w] = mT; s_red[4 + w] = mC; }
    s_c[tid] = centers[b * NBINS + tid];          // TPB == NBINS
    __syncthreads();
    if (tid == 0) {
        float aT = fmaxf(fmaxf(s_red[0], s_red[1]), fmaxf(s_red[2], s_red[3]));
        float aC = fmaxf(fmaxf(s_red[4], s_red[5]), fmaxf(s_red[6], s_red[7]));
        float mx = fmaxf(aT, aC), mn = fminf(aT, aC);
        float pad = mx + (mx - mn) + 1.0f;   // EPS = 1.0
        s_pad = pad;
        s_c[NBINS] = pad;                    // padded 257th center
        s_c[NBINS + 1] = pad;                // dead lanes for float4 tail
        s_c[NBINS + 2] = pad;
        s_c[NBINS + 3] = pad;
    }
    __syncthreads();
    const float pad = s_pad;

    // ---- phase 2: combine loads with pad; stage pixels to LDS;
    //      also compute this thread's (t - pad)^2 min for the pad center ----
    float t[P], min2[P];
    t[0] = m0 ? v0 : pad;
    t[1] = m1 ? v1 : pad;
    s_t[tid]       = t[0];
    s_t[TPB + tid] = t[1];
    min2[0] = min2[1] = INFINITY;
    float dp0 = t[0] - pad, dp1 = t[1] - pad;
    float pmin = fminf(dp0 * dp0, dp1 * dp1);     // dir1 partial for pad center
    __syncthreads();

    // ---- Loop A (dir2): per-pixel min over all 257 centers, no cross-lane ----
    const float4* s_c4 = (const float4*)s_c;
#pragma unroll 4
    for (int mq = 0; mq < 64; ++mq) {        // 64*4 = 256 real centers
        float4 c = s_c4[mq];
#pragma unroll
        for (int p = 0; p < P; ++p) {
            float d0 = t[p] - c.x, d1 = t[p] - c.y;
            float d2 = t[p] - c.z, d3 = t[p] - c.w;
            min2[p] = fminf(min2[p], fminf(fminf(d0 * d0, d1 * d1),
                                           fminf(d2 * d2, d3 * d3)));
        }
    }
    // pad center contribution to dir2 (dp* already computed)
    min2[0] = fminf(min2[0], dp0 * dp0);
    min2[1] = fminf(min2[1], dp1 * dp1);

    // ---- Loop B (dir1): exactly one real center per thread — uniform ----
    {
        const float4* s_t4 = (const float4*)s_t;
        float c = s_c[tid];
        float cmin = INFINITY;
#pragma unroll 8
        for (int j = 0; j < PXB / 4; ++j) {
            float4 v = s_t4[j];
            float d0 = v.x - c, d1 = v.y - c, d2 = v.z - c, d3 = v.w - c;
            cmin = fminf(cmin, fminf(fminf(d0 * d0, d1 * d1),
                                     fminf(d2 * d2, d3 * d3)));
        }
        atomicMin(&ws_dir1[b * NC + tid], __float_as_uint(cmin));
    }

    // ---- block reduce: dir2 sum + pad-center min, then one atomic each ----
    float acc = min2[0] + min2[1];
    for (int o = 32; o > 0; o >>= 1) {
        acc  += __shfl_down(acc, o);
        pmin  = fminf(pmin, __shfl_down(pmin, o));
    }
    __syncthreads();                          // s_red reuse safe-guard
    if ((tid & 63) == 0) { s_red[w] = acc; s_red[4 + w] = pmin; }
    __syncthreads();
    if (tid == 0) {
        atomicAdd(&ws_dir2[b], s_red[0] + s_red[1] + s_red[2] + s_red[3]);
        float pm = fminf(fminf(s_red[4], s_red[5]), fminf(s_red[6], s_red[7]));
        atomicMin(&ws_dir1[b * NC + NBINS], __float_as_uint(pm));
    }
}

__global__ __launch_bounds__(256) void kfinal(const float* __restrict__ ws,
                                              float* __restrict__ out) {
    const unsigned int* ws_dir1 = (const unsigned int*)(ws + WS_DIR1_OFF);
    const float*        ws_dir2 = ws + WS_DIR2_OFF;
    const int tid = threadIdx.x;
    float acc = 0.f;
    for (int i = tid; i < B * NC; i += 256)
        acc += __uint_as_float(ws_dir1[i]);   // monotone uint bits -> float
    if (tid < B) acc += ws_dir2[tid];
    for (int o = 32; o > 0; o >>= 1) acc += __shfl_down(acc, o);
    __shared__ float s[4];
    if ((tid & 63) == 0) s[tid >> 6] = acc;
    __syncthreads();
    if (tid == 0)
        out[0] = (s[0] + s[1] + s[2] + s[3]) * (1.0f / B);
}

extern "C" void kernel_launch(void* const* d_in, const int* in_sizes, int n_in,
                              void* d_out, int out_size, void* d_ws, size_t ws_size,
                              hipStream_t stream) {
    const float* target  = (const float*)d_in[0];
    const float* centers = (const float*)d_in[1];
    const int*   mask    = (const int*)d_in[2];
    float* out = (float*)d_out;
    float* ws  = (float*)d_ws;

    kmax<<<K1_BLOCKS, TPB, 0, stream>>>(target, mask, centers, ws);
    dim3 g2(K2_BPB, B);
    kmain<<<g2, TPB, 0, stream>>>(target, mask, centers, ws);
    kfinal<<<1, TPB, 0, stream>>>(ws, out);
}